// Round 7
// baseline (102.284 us; speedup 1.0000x reference)
//
#include <hip/hip_runtime.h>

// S6 selective scan: BT=8, L=8192, F=128, N=16
// y[b,t,f] = sum_n h[b,t,f,n]*C[b,t,n],  h = dA*h + dB*x  (diagonal A)
//
// y(t) = y_local(t) + sum_n E(t,n)*Hin(f,n),  E(t,n)=C(t,n)*exp(A_n*cumdelta(t))
//
// k_pre       : proj via wave-K-split (W scalar/uniform loads, no W-LDS),
//               LDS reduce of partials, wave0: prefix-sum -> G{dA,dB,C}, E, S
// k_scan      : ONE local scan (h0=0): y_local -> d_out, q  (no second scan pass)
// k_chunkscan : scan over chunks -> Hin (P = exp(A*S) on the fly)
// k_correct   : y += E @ Hin  (streaming rank-16 correction)

#define BTc   8
#define Lseq  8192
#define Fdim  128
#define Ndim  16
#define CH    128          // number of chunks
#define LC    64           // Lseq / CH

// grid (CH, BTc) x 256 thr. wave ks=tid>>6 handles K rows [32ks,32ks+32), lane=token.
__global__ __launch_bounds__(256) void k_pre(
    const float* __restrict__ x,
    const float* __restrict__ Wb, const float* __restrict__ bb,
    const float* __restrict__ Wc, const float* __restrict__ bc,
    const float* __restrict__ Wd, const float* __restrict__ bd,
    const float* __restrict__ A,  float* __restrict__ G,
    float* __restrict__ E, float* __restrict__ S)
{
    __shared__ float Pl[33][4][66];   // partials [j][ks][token], 34.8 KB
    const int tid = threadIdx.x;
    const int ks = tid >> 6, lane = tid & 63;
    const int c = blockIdx.x, b = blockIdx.y;
    const size_t tok0 = (size_t)b * Lseq + (size_t)c * LC;

    // ---- projection partials: lane=token, this wave's K-quarter ----
    const float4* xt = reinterpret_cast<const float4*>(x + (tok0 + lane) * Fdim + ks * 32);
    float acc[33];
#pragma unroll
    for (int j = 0; j < 33; ++j) acc[j] = 0.f;

#pragma unroll 2
    for (int kk = 0; kk < 8; ++kk) {
        float4 xv = xt[kk];
        const float* wbp = Wb + (ks * 32 + kk * 4) * 16;   // 4 K-rows x 16, uniform
        const float* wcp = Wc + (ks * 32 + kk * 4) * 16;
        const float* wdp = Wd + (ks * 32 + kk * 4);
#pragma unroll
        for (int j = 0; j < 16; ++j) {
            acc[j] = fmaf(xv.x, wbp[j],      acc[j]);
            acc[j] = fmaf(xv.y, wbp[16 + j], acc[j]);
            acc[j] = fmaf(xv.z, wbp[32 + j], acc[j]);
            acc[j] = fmaf(xv.w, wbp[48 + j], acc[j]);
            acc[16 + j] = fmaf(xv.x, wcp[j],      acc[16 + j]);
            acc[16 + j] = fmaf(xv.y, wcp[16 + j], acc[16 + j]);
            acc[16 + j] = fmaf(xv.z, wcp[32 + j], acc[16 + j]);
            acc[16 + j] = fmaf(xv.w, wcp[48 + j], acc[16 + j]);
        }
        acc[32] = fmaf(xv.x, wdp[0], acc[32]);
        acc[32] = fmaf(xv.y, wdp[1], acc[32]);
        acc[32] = fmaf(xv.z, wdp[2], acc[32]);
        acc[32] = fmaf(xv.w, wdp[3], acc[32]);
    }
#pragma unroll
    for (int j = 0; j < 33; ++j) Pl[j][ks][lane] = acc[j];
    __syncthreads();

    // ---- wave 0: reduce + postprocess (lane = token) ----
    if (tid < 64) {
        float s[33];
#pragma unroll
        for (int j = 0; j < 33; ++j)
            s[j] = (Pl[j][0][lane] + Pl[j][1][lane]) + (Pl[j][2][lane] + Pl[j][3][lane]);

        float v = s[32] + bd[0];
        float delta = fmaxf(v, 0.f) + log1pf(expf(-fabsf(v)));
        float cum = delta;                       // inclusive prefix over 64 tokens
#pragma unroll
        for (int off = 1; off < 64; off <<= 1) {
            float up = __shfl_up(cum, off);
            cum += (lane >= off) ? up : 0.f;
        }
        if (lane == LC - 1) S[b * CH + c] = cum;

        float out[48], Ev[16];
#pragma unroll
        for (int n = 0; n < 16; ++n) {
            float An = A[n];
            float dA = expf(delta * An);
            float Cn = s[16 + n] + bc[n];
            out[n]      = dA;
            out[16 + n] = (dA - 1.f) / An * (s[n] + bb[n]);
            out[32 + n] = Cn;
            Ev[n] = Cn * expf(An * cum);
        }
        float4* Gr = reinterpret_cast<float4*>(G + (tok0 + lane) * 48);
#pragma unroll
        for (int p = 0; p < 12; ++p)
            Gr[p] = make_float4(out[4*p], out[4*p+1], out[4*p+2], out[4*p+3]);
        float4* Ep = reinterpret_cast<float4*>(E + ((size_t)(b * CH + c) * LC + lane) * 16);
#pragma unroll
        for (int p = 0; p < 4; ++p)
            Ep[p] = make_float4(Ev[4*p], Ev[4*p+1], Ev[4*p+2], Ev[4*p+3]);
    }
}

// grid (CH, BTc) x 128 thr: f = tid. One scan pass: y_local + q.
__global__ __launch_bounds__(128, 2) void k_scan(
    const float* __restrict__ x, const float* __restrict__ G,
    float* __restrict__ y, float* __restrict__ q)
{
    __shared__ float Gl[LC][48];      // dA | dB | C, 12.3 KB
    const int c = blockIdx.x, b = blockIdx.y;
    const int f = threadIdx.x;
    const size_t tok0 = (size_t)b * Lseq + (size_t)c * LC;

    const float4* Gg = reinterpret_cast<const float4*>(G + tok0 * 48);
    float4* Gs = reinterpret_cast<float4*>(&Gl[0][0]);
    for (int idx = f; idx < LC * 12; idx += 128) Gs[idx] = Gg[idx];
    __syncthreads();

    float h[16];
#pragma unroll
    for (int n = 0; n < 16; ++n) h[n] = 0.f;

    const float* xp = x + tok0 * Fdim + f;
    float*       yp = y + tok0 * Fdim + f;
#pragma unroll 2
    for (int t = 0; t < LC; ++t) {
        float xv = xp[t * Fdim];
        const float4* gp4 = reinterpret_cast<const float4*>(&Gl[t][0]);
        float da[16], db[16], cc[16];
#pragma unroll
        for (int p = 0; p < 4; ++p) {
            float4 va = gp4[p], vb = gp4[4 + p], vc = gp4[8 + p];
            da[4*p] = va.x; da[4*p+1] = va.y; da[4*p+2] = va.z; da[4*p+3] = va.w;
            db[4*p] = vb.x; db[4*p+1] = vb.y; db[4*p+2] = vb.z; db[4*p+3] = vb.w;
            cc[4*p] = vc.x; cc[4*p+1] = vc.y; cc[4*p+2] = vc.z; cc[4*p+3] = vc.w;
        }
        float yacc = 0.f;
#pragma unroll
        for (int n = 0; n < 16; ++n) {
            h[n] = fmaf(da[n], h[n], db[n] * xv);
            yacc = fmaf(cc[n], h[n], yacc);
        }
        yp[t * Fdim] = yacc;
    }

    float4* qp = reinterpret_cast<float4*>(q + ((size_t)(b * CH + c) * Fdim + f) * 16);
#pragma unroll
    for (int p = 0; p < 4; ++p)
        qp[p] = make_float4(h[4*p], h[4*p+1], h[4*p+2], h[4*p+3]);
}

__global__ __launch_bounds__(256) void k_chunkscan(
    const float* __restrict__ q, const float* __restrict__ S,
    const float* __restrict__ A, float* __restrict__ Hin)
{
    int id = blockIdx.x * 256 + threadIdx.x;   // 16384 = 8*128*16
    int b  = id >> 11;
    int fn = id & 2047;
    int n  = id & 15;
    float An = A[n];
    float H = 0.f;
    size_t qb = (size_t)b * CH * 2048 + fn;
    const float* Sb = S + b * CH;
    for (int cg = 0; cg < CH; cg += 16) {
        float Sr[16], qr[16];
#pragma unroll
        for (int i = 0; i < 16; ++i) {
            Sr[i] = Sb[cg + i];
            qr[i] = q[qb + (size_t)(cg + i) * 2048];
        }
#pragma unroll
        for (int i = 0; i < 16; ++i) {
            Hin[qb + (size_t)(cg + i) * 2048] = H;
            H = fmaf(__expf(An * Sr[i]), H, qr[i]);
        }
    }
}

// grid (CH, BTc) x 128 thr: y += E @ Hin
__global__ __launch_bounds__(128, 2) void k_correct(
    const float* __restrict__ Hin, const float* __restrict__ E,
    float* __restrict__ y)
{
    __shared__ float El[LC][16];      // 4 KB
    const int c = blockIdx.x, b = blockIdx.y;
    const int f = threadIdx.x;

    const float4* Eg = reinterpret_cast<const float4*>(E + (size_t)(b * CH + c) * LC * 16);
    float4* Es = reinterpret_cast<float4*>(&El[0][0]);
    for (int i = f; i < LC * 4; i += 128) Es[i] = Eg[i];

    float hv[16];
    const float4* hp = reinterpret_cast<const float4*>(Hin + ((size_t)(b * CH + c) * Fdim + f) * 16);
#pragma unroll
    for (int p = 0; p < 4; ++p) {
        float4 t4 = hp[p];
        hv[4*p] = t4.x; hv[4*p+1] = t4.y; hv[4*p+2] = t4.z; hv[4*p+3] = t4.w;
    }
    __syncthreads();

    float* yp = y + ((size_t)b * Lseq + (size_t)c * LC) * Fdim + f;
#pragma unroll 4
    for (int t = 0; t < LC; ++t) {
        const float4* ep = reinterpret_cast<const float4*>(&El[t][0]);
        float acc = 0.f;
#pragma unroll
        for (int p = 0; p < 4; ++p) {
            float4 e4 = ep[p];
            acc = fmaf(e4.x, hv[4*p],     acc);
            acc = fmaf(e4.y, hv[4*p + 1], acc);
            acc = fmaf(e4.z, hv[4*p + 2], acc);
            acc = fmaf(e4.w, hv[4*p + 3], acc);
        }
        yp[t * Fdim] += acc;
    }
}

extern "C" void kernel_launch(void* const* d_in, const int* in_sizes, int n_in,
                              void* d_out, int out_size, void* d_ws, size_t ws_size,
                              hipStream_t stream) {
    const float* x  = (const float*)d_in[0];
    const float* Wb = (const float*)d_in[1];
    const float* bb = (const float*)d_in[2];
    const float* Wc = (const float*)d_in[3];
    const float* bc = (const float*)d_in[4];
    const float* Wd = (const float*)d_in[5];
    const float* bd = (const float*)d_in[6];
    const float* A  = (const float*)d_in[7];
    float* y = (float*)d_out;

    float* G   = (float*)d_ws;                           // 65536*48   = 12.6 MB
    float* q   = G   + (size_t)BTc * Lseq * 48;          // 8*128*2048 = 8.4 MB
    float* Hin = q   + (size_t)BTc * CH * Fdim * Ndim;   // 8*128*2048 = 8.4 MB
    float* E   = Hin + (size_t)BTc * CH * Fdim * Ndim;   // 65536*16   = 4.2 MB
    float* S   = E   + (size_t)BTc * Lseq * Ndim;        // 1024 floats

    k_pre<<<dim3(CH, BTc), 256, 0, stream>>>(x, Wb, bb, Wc, bc, Wd, bd, A, G, E, S);
    k_scan<<<dim3(CH, BTc), 128, 0, stream>>>(x, G, y, q);
    k_chunkscan<<<dim3(BTc * Fdim * Ndim / 256), 256, 0, stream>>>(q, S, A, Hin);
    k_correct<<<dim3(CH, BTc), 128, 0, stream>>>(Hin, E, y);
}

// Round 8
// 94.335 us; speedup vs baseline: 1.0843x; 1.0843x over previous
//
#include <hip/hip_runtime.h>

// S6 selective scan: BT=8, L=8192, F=128, N=16
// y[b,t,f] = sum_n h[b,t,f,n]*C[b,t,n],  h = dA*h + dB*x  (diagonal A)
//
// y(t) = y_local(t) + sum_n E(t,n)*Hin(f,n),  E(t,n)=C(t,n)*exp(A_n*cumdelta(t))
//
// k_pre       : proj (W in LDS, conflict-free, 4-way lane-K-split, 2 tok/thr)
//               -> G{dA,dB,C}, E = C*exp(A*cumdelta), S = chunk delta-sum
// k_scan      : 1 wave per chunk, 2 f/thread: local scan (h0=0)
//               -> y_local (d_out) + q.  12 b128 broadcasts/token, minimal.
// k_chunkscan : scan over chunks -> Hin (P = exp(A*S) on the fly)
// k_correct   : y += E @ Hin (1 wave/chunk, 2 f/thread; y rmw is L3-resident)

#define BTc   8
#define Lseq  8192
#define Fdim  128
#define Ndim  16
#define CH    128          // number of chunks per batch
#define LC    64           // Lseq / CH

// 512 blocks x 256 thr; thread=(t2,ks): tokens blk*128+t2 and +64, K-quarter ks
__global__ __launch_bounds__(256) void k_pre(
    const float* __restrict__ x,
    const float* __restrict__ Wb, const float* __restrict__ bb,
    const float* __restrict__ Wc, const float* __restrict__ bc,
    const float* __restrict__ Wd, const float* __restrict__ bd,
    const float* __restrict__ A,  float* __restrict__ G,
    float* __restrict__ E, float* __restrict__ S)
{
    __shared__ float Wl[33][4][36];   // 19 KB, ks-slices in distinct banks
    __shared__ float Dl[2][64];       // per-token delta (2 chunks)
    __shared__ float Cum[2][64];      // inclusive prefix of delta
    const int tid = threadIdx.x;
    for (int idx = tid; idx < 33 * 128; idx += 256) {
        int j = idx >> 7, k = idx & 127;
        float v;
        if (j < 16)      v = Wb[k * 16 + j];
        else if (j < 32) v = Wc[k * 16 + (j - 16)];
        else             v = Wd[k];
        Wl[j][k >> 5][k & 31] = v;
    }
    __syncthreads();

    const int t2 = tid >> 2, ks = tid & 3;
    const size_t gtok0 = (size_t)blockIdx.x * 128;
    const size_t tokA = gtok0 + t2;
    const float4* xA = reinterpret_cast<const float4*>(x + tokA * 128 + ks * 32);
    const float4* xB = reinterpret_cast<const float4*>(x + (tokA + 64) * 128 + ks * 32);

    float accA[33], accB[33];
#pragma unroll
    for (int j = 0; j < 33; ++j) { accA[j] = 0.f; accB[j] = 0.f; }

#pragma unroll 2
    for (int kk = 0; kk < 8; ++kk) {
        float4 a = xA[kk], b = xB[kk];
#pragma unroll
        for (int j = 0; j < 33; ++j) {
            float4 w = *reinterpret_cast<const float4*>(&Wl[j][ks][kk * 4]);
            accA[j] = fmaf(a.x, w.x, accA[j]);
            accA[j] = fmaf(a.y, w.y, accA[j]);
            accA[j] = fmaf(a.z, w.z, accA[j]);
            accA[j] = fmaf(a.w, w.w, accA[j]);
            accB[j] = fmaf(b.x, w.x, accB[j]);
            accB[j] = fmaf(b.y, w.y, accB[j]);
            accB[j] = fmaf(b.z, w.z, accB[j]);
            accB[j] = fmaf(b.w, w.w, accB[j]);
        }
    }

    float sel[33];
#pragma unroll
    for (int j = 0; j < 33; ++j) {
        accA[j] += __shfl_xor(accA[j], 1);
        accA[j] += __shfl_xor(accA[j], 2);
        accB[j] += __shfl_xor(accB[j], 1);
        accB[j] += __shfl_xor(accB[j], 2);
        sel[j] = (ks & 1) ? accB[j] : accA[j];
    }

    float Cv[16];                        // kept live across syncs (ks<2 lanes)
    if (ks < 2) {
        const size_t tok = gtok0 + (size_t)ks * 64 + t2;
        float v = sel[32] + bd[0];
        float delta = fmaxf(v, 0.f) + log1pf(expf(-fabsf(v)));
        Dl[ks][t2] = delta;
        float out[48];
#pragma unroll
        for (int n = 0; n < 16; ++n) {
            float An = A[n];
            float dA = expf(delta * An);
            Cv[n] = sel[16 + n] + bc[n];
            out[n]      = dA;
            out[16 + n] = (dA - 1.f) / An * (sel[n] + bb[n]);
            out[32 + n] = Cv[n];
        }
        float4* Gr = reinterpret_cast<float4*>(G + tok * 48);
#pragma unroll
        for (int p = 0; p < 12; ++p)
            Gr[p] = make_float4(out[4*p], out[4*p+1], out[4*p+2], out[4*p+3]);
    }
    __syncthreads();

    // inclusive prefix of delta per chunk (waves 0,1; lane = token)
    if (tid < 128) {
        const int w = tid >> 6, lane = tid & 63;
        float cum = Dl[w][lane];
#pragma unroll
        for (int off = 1; off < 64; off <<= 1) {
            float up = __shfl_up(cum, off);
            cum += (lane >= off) ? up : 0.f;
        }
        Cum[w][lane] = cum;
        if (lane == 63) S[blockIdx.x * 2 + w] = cum;
    }
    __syncthreads();

    if (ks < 2) {
        const size_t chunk = (size_t)blockIdx.x * 2 + ks;
        float cumv = Cum[ks][t2];
        float Ev[16];
#pragma unroll
        for (int n = 0; n < 16; ++n)
            Ev[n] = Cv[n] * expf(A[n] * cumv);
        float4* Ep = reinterpret_cast<float4*>(E + (chunk * 64 + t2) * 16);
#pragma unroll
        for (int p = 0; p < 4; ++p)
            Ep[p] = make_float4(Ev[4*p], Ev[4*p+1], Ev[4*p+2], Ev[4*p+3]);
    }
}

// grid (CH, BTc) x 64 thr: ONE wave per chunk, lane owns f = lane, lane+64.
__global__ __launch_bounds__(64) void k_scan(
    const float* __restrict__ x, const float* __restrict__ G,
    float* __restrict__ y, float* __restrict__ q)
{
    __shared__ float Gl[LC][48];      // dA | dB | C, 12.3 KB
    const int c = blockIdx.x, b = blockIdx.y;
    const int lane = threadIdx.x;
    const size_t tok0 = (size_t)b * Lseq + (size_t)c * LC;

    const float4* Gg = reinterpret_cast<const float4*>(G + tok0 * 48);
    float4* Gs = reinterpret_cast<float4*>(&Gl[0][0]);
    for (int idx = lane; idx < LC * 12; idx += 64) Gs[idx] = Gg[idx];
    __syncthreads();

    float h0[16], h1[16];
#pragma unroll
    for (int n = 0; n < 16; ++n) { h0[n] = 0.f; h1[n] = 0.f; }

    const float* xs = x + tok0 * Fdim;
    float*       yp = y + tok0 * Fdim;
#pragma unroll 2
    for (int t = 0; t < LC; ++t) {
        float xv0 = xs[t * Fdim + lane];
        float xv1 = xs[t * Fdim + lane + 64];
        const float4* gp4 = reinterpret_cast<const float4*>(&Gl[t][0]);
        float da[16], db[16], cc[16];
#pragma unroll
        for (int p = 0; p < 4; ++p) {
            float4 va = gp4[p], vb = gp4[4 + p], vc = gp4[8 + p];
            da[4*p] = va.x; da[4*p+1] = va.y; da[4*p+2] = va.z; da[4*p+3] = va.w;
            db[4*p] = vb.x; db[4*p+1] = vb.y; db[4*p+2] = vb.z; db[4*p+3] = vb.w;
            cc[4*p] = vc.x; cc[4*p+1] = vc.y; cc[4*p+2] = vc.z; cc[4*p+3] = vc.w;
        }
        float y0 = 0.f, y1 = 0.f;
#pragma unroll
        for (int n = 0; n < 16; ++n) {
            h0[n] = fmaf(da[n], h0[n], db[n] * xv0);
            h1[n] = fmaf(da[n], h1[n], db[n] * xv1);
            y0 = fmaf(cc[n], h0[n], y0);
            y1 = fmaf(cc[n], h1[n], y1);
        }
        yp[t * Fdim + lane]      = y0;
        yp[t * Fdim + lane + 64] = y1;
    }

    float4* qp0 = reinterpret_cast<float4*>(q + ((size_t)(b * CH + c) * Fdim + lane) * 16);
    float4* qp1 = reinterpret_cast<float4*>(q + ((size_t)(b * CH + c) * Fdim + lane + 64) * 16);
#pragma unroll
    for (int p = 0; p < 4; ++p) {
        qp0[p] = make_float4(h0[4*p], h0[4*p+1], h0[4*p+2], h0[4*p+3]);
        qp1[p] = make_float4(h1[4*p], h1[4*p+1], h1[4*p+2], h1[4*p+3]);
    }
}

__global__ __launch_bounds__(256) void k_chunkscan(
    const float* __restrict__ q, const float* __restrict__ S,
    const float* __restrict__ A, float* __restrict__ Hin)
{
    int id = blockIdx.x * 256 + threadIdx.x;   // 16384 = 8*128*16
    int b  = id >> 11;
    int fn = id & 2047;
    int n  = id & 15;
    float An = A[n];
    float H = 0.f;
    size_t qb = (size_t)b * CH * 2048 + fn;
    const float* Sb = S + b * CH;
    for (int cg = 0; cg < CH; cg += 16) {
        float Sr[16], qr[16];
#pragma unroll
        for (int i = 0; i < 16; ++i) {
            Sr[i] = Sb[cg + i];
            qr[i] = q[qb + (size_t)(cg + i) * 2048];
        }
#pragma unroll
        for (int i = 0; i < 16; ++i) {
            Hin[qb + (size_t)(cg + i) * 2048] = H;
            H = fmaf(__expf(An * Sr[i]), H, qr[i]);
        }
    }
}

// grid (CH, BTc) x 64 thr: y += E @ Hin, 1 wave/chunk, 2 f/thread
__global__ __launch_bounds__(64) void k_correct(
    const float* __restrict__ Hin, const float* __restrict__ E,
    float* __restrict__ y)
{
    __shared__ float El[LC][16];      // 4 KB
    const int c = blockIdx.x, b = blockIdx.y;
    const int lane = threadIdx.x;

    const float4* Eg = reinterpret_cast<const float4*>(E + (size_t)(b * CH + c) * LC * 16);
    float4* Es = reinterpret_cast<float4*>(&El[0][0]);
    for (int i = lane; i < LC * 4; i += 64) Es[i] = Eg[i];

    float hv0[16], hv1[16];
    const float4* hp0 = reinterpret_cast<const float4*>(Hin + ((size_t)(b * CH + c) * Fdim + lane) * 16);
    const float4* hp1 = reinterpret_cast<const float4*>(Hin + ((size_t)(b * CH + c) * Fdim + lane + 64) * 16);
#pragma unroll
    for (int p = 0; p < 4; ++p) {
        float4 a = hp0[p], bb4 = hp1[p];
        hv0[4*p] = a.x; hv0[4*p+1] = a.y; hv0[4*p+2] = a.z; hv0[4*p+3] = a.w;
        hv1[4*p] = bb4.x; hv1[4*p+1] = bb4.y; hv1[4*p+2] = bb4.z; hv1[4*p+3] = bb4.w;
    }
    __syncthreads();

    float* yp = y + ((size_t)b * Lseq + (size_t)c * LC) * Fdim;
#pragma unroll 2
    for (int t = 0; t < LC; ++t) {
        const float4* ep = reinterpret_cast<const float4*>(&El[t][0]);
        float a0 = 0.f, a1 = 0.f;
#pragma unroll
        for (int p = 0; p < 4; ++p) {
            float4 e4 = ep[p];
            a0 = fmaf(e4.x, hv0[4*p],   a0); a1 = fmaf(e4.x, hv1[4*p],   a1);
            a0 = fmaf(e4.y, hv0[4*p+1], a0); a1 = fmaf(e4.y, hv1[4*p+1], a1);
            a0 = fmaf(e4.z, hv0[4*p+2], a0); a1 = fmaf(e4.z, hv1[4*p+2], a1);
            a0 = fmaf(e4.w, hv0[4*p+3], a0); a1 = fmaf(e4.w, hv1[4*p+3], a1);
        }
        yp[t * Fdim + lane]      += a0;
        yp[t * Fdim + lane + 64] += a1;
    }
}

extern "C" void kernel_launch(void* const* d_in, const int* in_sizes, int n_in,
                              void* d_out, int out_size, void* d_ws, size_t ws_size,
                              hipStream_t stream) {
    const float* x  = (const float*)d_in[0];
    const float* Wb = (const float*)d_in[1];
    const float* bb = (const float*)d_in[2];
    const float* Wc = (const float*)d_in[3];
    const float* bc = (const float*)d_in[4];
    const float* Wd = (const float*)d_in[5];
    const float* bd = (const float*)d_in[6];
    const float* A  = (const float*)d_in[7];
    float* y = (float*)d_out;

    float* G   = (float*)d_ws;                           // 65536*48   = 12.6 MB
    float* q   = G   + (size_t)BTc * Lseq * 48;          // 8*128*2048 = 8.4 MB
    float* Hin = q   + (size_t)BTc * CH * Fdim * Ndim;   // 8*128*2048 = 8.4 MB
    float* E   = Hin + (size_t)BTc * CH * Fdim * Ndim;   // 65536*16   = 4.2 MB
    float* S   = E   + (size_t)BTc * Lseq * Ndim;        // 1024 floats

    k_pre<<<dim3(512), 256, 0, stream>>>(x, Wb, bb, Wc, bc, Wd, bd, A, G, E, S);
    k_scan<<<dim3(CH, BTc), 64, 0, stream>>>(x, G, y, q);
    k_chunkscan<<<dim3(BTc * Fdim * Ndim / 256), 256, 0, stream>>>(q, S, A, Hin);
    k_correct<<<dim3(CH, BTc), 64, 0, stream>>>(Hin, E, y);
}

// Round 9
// 90.657 us; speedup vs baseline: 1.1283x; 1.0406x over previous
//
#include <hip/hip_runtime.h>
#include <hip/hip_bf16.h>

// S6 selective scan: BT=8, L=8192, F=128, N=16
// y[b,t,f] = sum_n h[b,t,f,n]*C[b,t,n],  h = dA*h + dB*x  (diagonal A)
//
// y(t) = y_local(t) + sum_n E(t,n)*Hin(f,n),  E(t,n)=C(t,n)*exp(A_n*cumdelta(t))
//
// k_pre       : proj (W in LDS, conflict-free, 4-way lane-K-split, 2 tok/thr)
//               -> G{dA,dB,C} packed bf16 (24 u32/token), E (f32), S
// k_scan      : ONE local scan pass per chunk: x-tile + G-tile staged in LDS
//               (all chain latencies short/LDS) -> y_local (d_out) + q
// k_chunkscan : scan over chunks -> Hin (P = exp(A*S) on the fly)
// k_correct   : y += E @ Hin (streaming rank-16 correction)

#define BTc   8
#define Lseq  8192
#define Fdim  128
#define Ndim  16
#define CH    128          // number of chunks per batch
#define LC    64           // Lseq / CH

__device__ inline uint32_t pkbf(float a, float b) {
    union { __hip_bfloat162 h; uint32_t u; } cv;
    cv.h.x = __float2bfloat16(a);
    cv.h.y = __float2bfloat16(b);
    return cv.u;
}
__device__ inline void upbf(uint32_t u, float& lo, float& hi) {
    union { uint32_t i; float f; } a, b;
    a.i = u << 16; b.i = u & 0xffff0000u;
    lo = a.f; hi = b.f;
}

// 512 blocks x 256 thr; thread=(t2,ks): tokens blk*128+t2 and +64, K-quarter ks
__global__ __launch_bounds__(256) void k_pre(
    const float* __restrict__ x,
    const float* __restrict__ Wb, const float* __restrict__ bb,
    const float* __restrict__ Wc, const float* __restrict__ bc,
    const float* __restrict__ Wd, const float* __restrict__ bd,
    const float* __restrict__ A,  uint32_t* __restrict__ G,
    float* __restrict__ E, float* __restrict__ S)
{
    __shared__ float Wl[33][4][36];   // 19 KB, ks-slices in distinct banks
    __shared__ float Dl[2][64];       // per-token delta (2 chunks)
    __shared__ float Cum[2][64];      // inclusive prefix of delta
    const int tid = threadIdx.x;
    for (int idx = tid; idx < 33 * 128; idx += 256) {
        int j = idx >> 7, k = idx & 127;
        float v;
        if (j < 16)      v = Wb[k * 16 + j];
        else if (j < 32) v = Wc[k * 16 + (j - 16)];
        else             v = Wd[k];
        Wl[j][k >> 5][k & 31] = v;
    }
    __syncthreads();

    const int t2 = tid >> 2, ks = tid & 3;
    const size_t gtok0 = (size_t)blockIdx.x * 128;
    const size_t tokA = gtok0 + t2;
    const float4* xA = reinterpret_cast<const float4*>(x + tokA * 128 + ks * 32);
    const float4* xB = reinterpret_cast<const float4*>(x + (tokA + 64) * 128 + ks * 32);

    float accA[33], accB[33];
#pragma unroll
    for (int j = 0; j < 33; ++j) { accA[j] = 0.f; accB[j] = 0.f; }

#pragma unroll 2
    for (int kk = 0; kk < 8; ++kk) {
        float4 a = xA[kk], b = xB[kk];
#pragma unroll
        for (int j = 0; j < 33; ++j) {
            float4 w = *reinterpret_cast<const float4*>(&Wl[j][ks][kk * 4]);
            accA[j] = fmaf(a.x, w.x, accA[j]);
            accA[j] = fmaf(a.y, w.y, accA[j]);
            accA[j] = fmaf(a.z, w.z, accA[j]);
            accA[j] = fmaf(a.w, w.w, accA[j]);
            accB[j] = fmaf(b.x, w.x, accB[j]);
            accB[j] = fmaf(b.y, w.y, accB[j]);
            accB[j] = fmaf(b.z, w.z, accB[j]);
            accB[j] = fmaf(b.w, w.w, accB[j]);
        }
    }

    float sel[33];
#pragma unroll
    for (int j = 0; j < 33; ++j) {
        accA[j] += __shfl_xor(accA[j], 1);
        accA[j] += __shfl_xor(accA[j], 2);
        accB[j] += __shfl_xor(accB[j], 1);
        accB[j] += __shfl_xor(accB[j], 2);
        sel[j] = (ks & 1) ? accB[j] : accA[j];
    }

    float Cv[16];                        // kept live across syncs (ks<2 lanes)
    if (ks < 2) {
        const size_t tok = gtok0 + (size_t)ks * 64 + t2;
        float v = sel[32] + bd[0];
        float delta = fmaxf(v, 0.f) + log1pf(expf(-fabsf(v)));
        Dl[ks][t2] = delta;
        float out[48];
#pragma unroll
        for (int n = 0; n < 16; ++n) {
            float An = A[n];
            float dA = expf(delta * An);
            Cv[n] = sel[16 + n] + bc[n];
            out[n]      = dA;
            out[16 + n] = (dA - 1.f) / An * (sel[n] + bb[n]);
            out[32 + n] = Cv[n];
        }
        uint32_t gw[24];
#pragma unroll
        for (int p = 0; p < 24; ++p) gw[p] = pkbf(out[2*p], out[2*p+1]);
        uint4* Gr = reinterpret_cast<uint4*>(G + tok * 24);
#pragma unroll
        for (int p = 0; p < 6; ++p)
            Gr[p] = make_uint4(gw[4*p], gw[4*p+1], gw[4*p+2], gw[4*p+3]);
    }
    __syncthreads();

    // inclusive prefix of delta per chunk (waves 0,1; lane = token)
    if (tid < 128) {
        const int w = tid >> 6, lane = tid & 63;
        float cum = Dl[w][lane];
#pragma unroll
        for (int off = 1; off < 64; off <<= 1) {
            float up = __shfl_up(cum, off);
            cum += (lane >= off) ? up : 0.f;
        }
        Cum[w][lane] = cum;
        if (lane == 63) S[blockIdx.x * 2 + w] = cum;
    }
    __syncthreads();

    if (ks < 2) {
        const size_t chunk = (size_t)blockIdx.x * 2 + ks;
        float cumv = Cum[ks][t2];
        float Ev[16];
#pragma unroll
        for (int n = 0; n < 16; ++n)
            Ev[n] = Cv[n] * expf(A[n] * cumv);
        float4* Ep = reinterpret_cast<float4*>(E + (chunk * 64 + t2) * 16);
#pragma unroll
        for (int p = 0; p < 4; ++p)
            Ep[p] = make_float4(Ev[4*p], Ev[4*p+1], Ev[4*p+2], Ev[4*p+3]);
    }
}

// grid (CH, BTc) x 128 thr: one scan pass, x+G from LDS. y_local + q.
__global__ __launch_bounds__(128) void k_scan(
    const float* __restrict__ x, const uint32_t* __restrict__ G,
    float* __restrict__ y, float* __restrict__ q)
{
    __shared__ float    Xl[LC][Fdim];   // 32 KB
    __shared__ uint32_t Gl[LC][24];     // 6 KB: dA|dB|C bf16-packed
    const int c = blockIdx.x, b = blockIdx.y;
    const int f = threadIdx.x;
    const size_t tok0 = (size_t)b * Lseq + (size_t)c * LC;

    const float4* xg = reinterpret_cast<const float4*>(x + tok0 * Fdim);
    float4* xs = reinterpret_cast<float4*>(&Xl[0][0]);
    for (int i = f; i < LC * Fdim / 4; i += 128) xs[i] = xg[i];
    const uint4* gg = reinterpret_cast<const uint4*>(G + tok0 * 24);
    uint4* gs = reinterpret_cast<uint4*>(&Gl[0][0]);
    for (int i = f; i < LC * 6; i += 128) gs[i] = gg[i];
    __syncthreads();

    float h[16];
#pragma unroll
    for (int n = 0; n < 16; ++n) h[n] = 0.f;

    float* yp = y + tok0 * Fdim + f;
#pragma unroll 4
    for (int t = 0; t < LC; ++t) {
        float xv = Xl[t][f];
        const uint4* gp = reinterpret_cast<const uint4*>(&Gl[t][0]);
        uint4 g0 = gp[0], g1 = gp[1], g2 = gp[2], g3 = gp[3], g4 = gp[4], g5 = gp[5];
        float da[16], db[16], cc[16];
        upbf(g0.x, da[0], da[1]);  upbf(g0.y, da[2],  da[3]);
        upbf(g0.z, da[4], da[5]);  upbf(g0.w, da[6],  da[7]);
        upbf(g1.x, da[8], da[9]);  upbf(g1.y, da[10], da[11]);
        upbf(g1.z, da[12], da[13]); upbf(g1.w, da[14], da[15]);
        upbf(g2.x, db[0], db[1]);  upbf(g2.y, db[2],  db[3]);
        upbf(g2.z, db[4], db[5]);  upbf(g2.w, db[6],  db[7]);
        upbf(g3.x, db[8], db[9]);  upbf(g3.y, db[10], db[11]);
        upbf(g3.z, db[12], db[13]); upbf(g3.w, db[14], db[15]);
        upbf(g4.x, cc[0], cc[1]);  upbf(g4.y, cc[2],  cc[3]);
        upbf(g4.z, cc[4], cc[5]);  upbf(g4.w, cc[6],  cc[7]);
        upbf(g5.x, cc[8], cc[9]);  upbf(g5.y, cc[10], cc[11]);
        upbf(g5.z, cc[12], cc[13]); upbf(g5.w, cc[14], cc[15]);
        float yacc = 0.f;
#pragma unroll
        for (int n = 0; n < 16; ++n) {
            h[n] = fmaf(da[n], h[n], db[n] * xv);
            yacc = fmaf(cc[n], h[n], yacc);
        }
        yp[t * Fdim] = yacc;
    }

    float4* qp = reinterpret_cast<float4*>(q + ((size_t)(b * CH + c) * Fdim + f) * 16);
#pragma unroll
    for (int p = 0; p < 4; ++p)
        qp[p] = make_float4(h[4*p], h[4*p+1], h[4*p+2], h[4*p+3]);
}

__global__ __launch_bounds__(256) void k_chunkscan(
    const float* __restrict__ q, const float* __restrict__ S,
    const float* __restrict__ A, float* __restrict__ Hin)
{
    int id = blockIdx.x * 256 + threadIdx.x;   // 16384 = 8*128*16
    int b  = id >> 11;
    int fn = id & 2047;
    int n  = id & 15;
    float An = A[n];
    float H = 0.f;
    size_t qb = (size_t)b * CH * 2048 + fn;
    const float* Sb = S + b * CH;
    for (int cg = 0; cg < CH; cg += 16) {
        float Sr[16], qr[16];
#pragma unroll
        for (int i = 0; i < 16; ++i) {
            Sr[i] = Sb[cg + i];
            qr[i] = q[qb + (size_t)(cg + i) * 2048];
        }
#pragma unroll
        for (int i = 0; i < 16; ++i) {
            Hin[qb + (size_t)(cg + i) * 2048] = H;
            H = fmaf(__expf(An * Sr[i]), H, qr[i]);
        }
    }
}

// grid (CH, BTc) x 128 thr: y += E @ Hin
__global__ __launch_bounds__(128) void k_correct(
    const float* __restrict__ Hin, const float* __restrict__ E,
    float* __restrict__ y)
{
    __shared__ float El[LC][16];      // 4 KB
    const int c = blockIdx.x, b = blockIdx.y;
    const int f = threadIdx.x;

    const float4* Eg = reinterpret_cast<const float4*>(E + (size_t)(b * CH + c) * LC * 16);
    float4* Es = reinterpret_cast<float4*>(&El[0][0]);
    for (int i = f; i < LC * 4; i += 128) Es[i] = Eg[i];

    float hv[16];
    const float4* hp = reinterpret_cast<const float4*>(Hin + ((size_t)(b * CH + c) * Fdim + f) * 16);
#pragma unroll
    for (int p = 0; p < 4; ++p) {
        float4 t4 = hp[p];
        hv[4*p] = t4.x; hv[4*p+1] = t4.y; hv[4*p+2] = t4.z; hv[4*p+3] = t4.w;
    }
    __syncthreads();

    float* yp = y + ((size_t)b * Lseq + (size_t)c * LC) * Fdim + f;
#pragma unroll 4
    for (int t = 0; t < LC; ++t) {
        const float4* ep = reinterpret_cast<const float4*>(&El[t][0]);
        float acc = 0.f;
#pragma unroll
        for (int p = 0; p < 4; ++p) {
            float4 e4 = ep[p];
            acc = fmaf(e4.x, hv[4*p],     acc);
            acc = fmaf(e4.y, hv[4*p + 1], acc);
            acc = fmaf(e4.z, hv[4*p + 2], acc);
            acc = fmaf(e4.w, hv[4*p + 3], acc);
        }
        yp[t * Fdim] += acc;
    }
}

extern "C" void kernel_launch(void* const* d_in, const int* in_sizes, int n_in,
                              void* d_out, int out_size, void* d_ws, size_t ws_size,
                              hipStream_t stream) {
    const float* x  = (const float*)d_in[0];
    const float* Wb = (const float*)d_in[1];
    const float* bb = (const float*)d_in[2];
    const float* Wc = (const float*)d_in[3];
    const float* bc = (const float*)d_in[4];
    const float* Wd = (const float*)d_in[5];
    const float* bd = (const float*)d_in[6];
    const float* A  = (const float*)d_in[7];
    float* y = (float*)d_out;

    uint32_t* G = (uint32_t*)d_ws;                        // 65536*24 u32 = 6.3 MB
    float* q    = (float*)(G + (size_t)BTc * Lseq * 24);  // 8*128*2048 = 8.4 MB
    float* Hin  = q   + (size_t)BTc * CH * Fdim * Ndim;   // 8*128*2048 = 8.4 MB
    float* E    = Hin + (size_t)BTc * CH * Fdim * Ndim;   // 65536*16   = 4.2 MB
    float* S    = E   + (size_t)BTc * Lseq * Ndim;        // 1024 floats

    k_pre<<<dim3(512), 256, 0, stream>>>(x, Wb, bb, Wc, bc, Wd, bd, A, G, E, S);
    k_scan<<<dim3(CH, BTc), 128, 0, stream>>>(x, G, y, q);
    k_chunkscan<<<dim3(BTc * Fdim * Ndim / 256), 256, 0, stream>>>(q, S, A, Hin);
    k_correct<<<dim3(CH, BTc), 128, 0, stream>>>(Hin, E, y);
}